// Round 12
// baseline (929.563 us; speedup 1.0000x reference)
//
#include <hip/hip_runtime.h>
#include <hip/hip_bf16.h>
#include <hip/hip_fp16.h>

#define USER_N   100000
#define ITEM_N   200000
#define N_NODES  300000           // USER_N + ITEM_N
#define LATDIM   64
#define N_EDGES  9600000
#define N_LAYERS 3

// coarse bucket = row >> 11  (2048 rows ~= 400KB colval region)
#define CSHIFT   11
#define CROWS    2048
#define NCOARSE  ((N_NODES + CROWS - 1) / CROWS)   // 147
#define CHUNK    4096
#define NCHUNKS  ((N_EDGES + CHUNK - 1) / CHUNK)    // 2344
#define GP1      1024                               // p1 grid
#define GP4      1024                               // p4 grid (4 blocks/CU at 39KB)

// ---- bf16 helpers (RNE) ----
__device__ __forceinline__ unsigned short f2bf(float f) {
    unsigned int u = __float_as_uint(f);
    u += 0x7FFFu + ((u >> 16) & 1u);
    return (unsigned short)(u >> 16);
}
__device__ __forceinline__ float bf2f(unsigned short h) {
    return __uint_as_float(((unsigned int)h) << 16);
}

// ---------------------------------------------------------------------------
// convert concat(u,i) fp32 -> bf16 cur0
// ---------------------------------------------------------------------------
__global__ void cvt_concat_kernel(const float* __restrict__ u,
                                  const float* __restrict__ it,
                                  ushort4* __restrict__ cur0,
                                  int n4u, int n4total) {
    int stride = gridDim.x * blockDim.x;
    for (int i = blockIdx.x * blockDim.x + threadIdx.x; i < n4total; i += stride) {
        float4 v = (i < n4u) ? ((const float4*)u)[i]
                             : ((const float4*)it)[i - n4u];
        ushort4 o;
        o.x = f2bf(v.x); o.y = f2bf(v.y); o.z = f2bf(v.z); o.w = f2bf(v.w);
        cur0[i] = o;
    }
}

// ---------------------------------------------------------------------------
// p1: per-chunk coarse histogram -> cntRaw[bucket * NCHUNKS + chunk]
// (LDS atomics only — per-edge global atomics write through to HBM)
// ---------------------------------------------------------------------------
__global__ __launch_bounds__(256)
void p1_hist_kernel(const int* __restrict__ row, int* __restrict__ cntRaw) {
    __shared__ int h[NCOARSE];
    int t = threadIdx.x;
    for (int k = blockIdx.x; k < NCHUNKS; k += gridDim.x) {
        for (int i = t; i < NCOARSE; i += 256) h[i] = 0;
        __syncthreads();
        int e0 = k * CHUNK;
        int e1 = e0 + CHUNK; if (e1 > N_EDGES) e1 = N_EDGES;
        for (int e = e0 + t; e < e1; e += 256)
            atomicAdd(&h[row[e] >> CSHIFT], 1);
        __syncthreads();
        for (int i = t; i < NCOARSE; i += 256)
            cntRaw[i * NCHUNKS + k] = h[i];
        __syncthreads();
    }
}

// ---------------------------------------------------------------------------
// p2: per-bucket exclusive scan over its NCHUNKS counts -> cntScan (relative),
// bucket total -> btot.  One 1024-thread block per bucket; 3 elems/thread.
// ---------------------------------------------------------------------------
__global__ __launch_bounds__(1024)
void p2_scanchunks_kernel(const int* __restrict__ cntRaw,
                          int* __restrict__ cntScan,
                          int* __restrict__ btot) {
    __shared__ int lds[1024];
    int b = blockIdx.x, t = threadIdx.x;
    const int base = t * 3;
    int v0 = 0, v1 = 0, v2 = 0;
    if (base     < NCHUNKS) v0 = cntRaw[b * NCHUNKS + base];
    if (base + 1 < NCHUNKS) v1 = cntRaw[b * NCHUNKS + base + 1];
    if (base + 2 < NCHUNKS) v2 = cntRaw[b * NCHUNKS + base + 2];
    int s = v0 + v1 + v2;
    lds[t] = s;
    __syncthreads();
    for (int off = 1; off < 1024; off <<= 1) {
        int add = (t >= off) ? lds[t - off] : 0;
        __syncthreads();
        lds[t] += add;
        __syncthreads();
    }
    int ex = lds[t] - s;
    if (base     < NCHUNKS) cntScan[b * NCHUNKS + base]     = ex;
    if (base + 1 < NCHUNKS) cntScan[b * NCHUNKS + base + 1] = ex + v0;
    if (base + 2 < NCHUNKS) cntScan[b * NCHUNKS + base + 2] = ex + v0 + v1;
    if (t == 1023) btot[b] = lds[1023];
}

// ---------------------------------------------------------------------------
// p3: exclusive scan of NCOARSE totals -> cbase; rowPtr[N]=E
// ---------------------------------------------------------------------------
__global__ void p3_scancoarse_kernel(const int* __restrict__ btot,
                                     int* __restrict__ cbase,
                                     int* __restrict__ rowPtr) {
    __shared__ int lds[256];
    int t = threadIdx.x;
    int v = (t < NCOARSE) ? btot[t] : 0;
    lds[t] = v;
    __syncthreads();
    for (int off = 1; off < 256; off <<= 1) {
        int add = (t >= off) ? lds[t - off] : 0;
        __syncthreads();
        lds[t] += add;
        __syncthreads();
    }
    if (t < NCOARSE) cbase[t] = lds[t] - v;
    if (t == NCOARSE - 1) cbase[NCOARSE] = lds[t];
    if (t == 0) rowPtr[N_NODES] = N_EDGES;
}

// ---------------------------------------------------------------------------
// p4: chunked coarse partition with COALESCED run flush. Entries placed in an
// LDS stage at within-chunk sorted positions (LDS cursors); flush resolves
// each slot's bucket via a 4KB byte-map (replaces the 16KB dst array; LDS
// 50->39KB -> 4 blocks/CU), dst = gcur[c] + (j - loff[c]).  No global atomics.
// key = row_local(11b)<<19 | col(19b)
// ---------------------------------------------------------------------------
__global__ __launch_bounds__(256)
void p4_scatter_kernel(const int*   __restrict__ row,
                       const int*   __restrict__ col,
                       const float* __restrict__ val,
                       const int*   __restrict__ cntRaw,
                       const int*   __restrict__ cntScan,
                       const int*   __restrict__ cbase,
                       int2*        __restrict__ tempA) {
    __shared__ int2 stage[CHUNK];               // 32 KB
    __shared__ unsigned char bmap[CHUNK];       // 4 KB
    __shared__ int  loff[NCOARSE];
    __shared__ int  lcur[NCOARSE];
    __shared__ int  gcur[NCOARSE];
    __shared__ int  sc[256];
    int t = threadIdx.x;
    for (int k = blockIdx.x; k < NCHUNKS; k += gridDim.x) {
        int hv = 0;
        if (t < NCOARSE) {
            hv = cntRaw[t * NCHUNKS + k];
            gcur[t] = cbase[t] + cntScan[t * NCHUNKS + k];
        }
        sc[t] = hv;
        __syncthreads();
        for (int off = 1; off < 256; off <<= 1) {
            int add = (t >= off) ? sc[t - off] : 0;
            __syncthreads();
            sc[t] += add;
            __syncthreads();
        }
        int exl = sc[t] - hv;
        if (t < NCOARSE) {
            loff[t] = exl;
            lcur[t] = exl;
        }
        __syncthreads();
        if (t < NCOARSE) {                      // fill bucket byte-map
            int e = exl + hv;
            for (int j = exl; j < e; ++j) bmap[j] = (unsigned char)t;
        }
        int e0 = k * CHUNK;
        int e1 = e0 + CHUNK; if (e1 > N_EDGES) e1 = N_EDGES;
        int n = e1 - e0;
        for (int e = e0 + t; e < e1; e += 256) {
            int r = row[e];
            int c = r >> CSHIFT;
            int p = atomicAdd(&lcur[c], 1);
            stage[p] = make_int2(((r & (CROWS - 1)) << 19) | col[e],
                                 __float_as_int(val[e]));
        }
        __syncthreads();
        for (int j = t; j < n; j += 256) {      // coalesced run flush
            int c = bmap[j];
            tempA[gcur[c] + (j - loff[c])] = stage[j];
        }
        __syncthreads();
    }
}

// ---------------------------------------------------------------------------
// passB: one 1024-thread block per coarse bucket. LDS hist of 2048 rows,
// LDS scan (emits rowPtr slice), LDS-cursor scatter into the bucket's
// exclusive colval region.  colval_c = col*32 (pre-scaled for ushort2
// indexing), colval_v = fp16(val).
// ---------------------------------------------------------------------------
__global__ __launch_bounds__(1024)
void passB_kernel(const int*  __restrict__ cbase,
                  const int2* __restrict__ tempA,
                  int*        __restrict__ colval_c,
                  unsigned short* __restrict__ colval_v,
                  int*        __restrict__ rowPtr) {
    __shared__ int hist[CROWS];     // 8 KB
    __shared__ int psum[1024];      // 4 KB
    __shared__ int curs[CROWS];     // 8 KB
    int c = blockIdx.x;
    int t = threadIdx.x;
    int beg = cbase[c], end = cbase[c + 1];

    hist[t] = 0; hist[t + 1024] = 0;
    __syncthreads();
    for (int i = beg + t; i < end; i += 1024)
        atomicAdd(&hist[((unsigned)tempA[i].x) >> 19], 1);
    __syncthreads();

    int b0 = hist[2 * t], b1 = hist[2 * t + 1];
    int tot = b0 + b1;
    psum[t] = tot;
    __syncthreads();
    for (int off = 1; off < 1024; off <<= 1) {
        int add = (t >= off) ? psum[t - off] : 0;
        __syncthreads();
        psum[t] += add;
        __syncthreads();
    }
    int ex = psum[t] - tot;              // exclusive over pairs
    int j0 = 2 * t, j1 = 2 * t + 1;
    int e0 = beg + ex, e1 = beg + ex + b0;
    curs[j0] = e0;
    curs[j1] = e1;
    int gr0 = c * CROWS + j0;
    int gr1 = c * CROWS + j1;
    if (gr0 < N_NODES) rowPtr[gr0] = e0;
    if (gr1 < N_NODES) rowPtr[gr1] = e1;
    __syncthreads();

    for (int i = beg + t; i < end; i += 1024) {
        int2 kv = tempA[i];
        int rl = ((unsigned)kv.x) >> 19;
        int pos = atomicAdd(&curs[rl], 1);
        colval_c[pos] = (kv.x & 0x7FFFF) << 5;                       // col*32
        colval_v[pos] = __half_as_ushort(__float2half(__int_as_float(kv.y)));
    }
}

// ---------------------------------------------------------------------------
// bf16 CSR SpMM: 32 lanes/row, lane q owns dims [2q,2q+2) (ushort2 gather,
// full 128B line per edge, E[max deg of 2 rows/wave] imbalance +9% vs +19%).
// 8 gathers in flight. colval_c pre-scaled col*32; val fp16.
// ---------------------------------------------------------------------------
__global__ void spmm_bf16_kernel(const int*  __restrict__ rp,
                                 const int*  __restrict__ cvc,
                                 const unsigned short* __restrict__ cvv,
                                 const ushort2* __restrict__ x2,
                                 ushort2*       __restrict__ y2) {
    int g = (blockIdx.x * blockDim.x + threadIdx.x) >> 5;   // row
    if (g >= N_NODES) return;
    int q = threadIdx.x & 31;
    int beg = rp[g];
    int end = rp[g + 1];
    const ushort2* xq = x2 + q;

    float s0 = 0.f, s1 = 0.f;
    int i = beg;
    for (; i + 8 <= end; i += 8) {
        int cc[8]; unsigned short vv[8]; ushort2 gg[8];
        #pragma unroll
        for (int k = 0; k < 8; ++k) cc[k] = cvc[i + k];
        #pragma unroll
        for (int k = 0; k < 8; ++k) vv[k] = cvv[i + k];
        #pragma unroll
        for (int k = 0; k < 8; ++k) gg[k] = xq[cc[k]];
        #pragma unroll
        for (int k = 0; k < 8; ++k) {
            float v = __half2float(__ushort_as_half(vv[k]));
            s0 += bf2f(gg[k].x) * v; s1 += bf2f(gg[k].y) * v;
        }
    }
    for (; i < end; ++i) {
        ushort2 gg = xq[cvc[i]];
        float v = __half2float(__ushort_as_half(cvv[i]));
        s0 += bf2f(gg.x) * v; s1 += bf2f(gg.y) * v;
    }

    ushort2 o;
    o.x = f2bf(s0); o.y = f2bf(s1);
    y2[(size_t)g * 32 + q] = o;
}

// ---------------------------------------------------------------------------
// fused layer-3 SpMM + final accumulation:
// acc[g] = emb[g] + c1[g] + c2[g] + (A @ c2)[g]    (fp32 out)
// ---------------------------------------------------------------------------
__global__ void spmm_bf16_final_kernel(const int*  __restrict__ rp,
                                       const int*  __restrict__ cvc,
                                       const unsigned short* __restrict__ cvv,
                                       const ushort2* __restrict__ x2,   // c2
                                       const ushort2* __restrict__ c1,
                                       const float2*  __restrict__ u2,
                                       const float2*  __restrict__ i2,
                                       float2*        __restrict__ acc2) {
    int g = (blockIdx.x * blockDim.x + threadIdx.x) >> 5;   // row
    if (g >= N_NODES) return;
    int q = threadIdx.x & 31;
    int beg = rp[g];
    int end = rp[g + 1];
    const ushort2* xq = x2 + q;

    float s0 = 0.f, s1 = 0.f;
    int i = beg;
    for (; i + 8 <= end; i += 8) {
        int cc[8]; unsigned short vv[8]; ushort2 gg[8];
        #pragma unroll
        for (int k = 0; k < 8; ++k) cc[k] = cvc[i + k];
        #pragma unroll
        for (int k = 0; k < 8; ++k) vv[k] = cvv[i + k];
        #pragma unroll
        for (int k = 0; k < 8; ++k) gg[k] = xq[cc[k]];
        #pragma unroll
        for (int k = 0; k < 8; ++k) {
            float v = __half2float(__ushort_as_half(vv[k]));
            s0 += bf2f(gg[k].x) * v; s1 += bf2f(gg[k].y) * v;
        }
    }
    for (; i < end; ++i) {
        ushort2 gg = xq[cvc[i]];
        float v = __half2float(__ushort_as_half(cvv[i]));
        s0 += bf2f(gg.x) * v; s1 += bf2f(gg.y) * v;
    }

    size_t o = (size_t)g * 32 + q;
    float2 e = (g < USER_N) ? u2[o] : i2[o - (size_t)USER_N * 32];
    ushort2 a = c1[o];
    ushort2 b = x2[o];           // c2 own-row
    float2 r;
    r.x = e.x + bf2f(a.x) + bf2f(b.x) + s0;
    r.y = e.y + bf2f(a.y) + bf2f(b.y) + s1;
    acc2[o] = r;
}

// ---------------------------------------------------------------------------
// Fallback path: fp32 COO atomic SpMM + acc add (used if ws too small)
// ---------------------------------------------------------------------------
__global__ void copy_concat_kernel(const float* __restrict__ u,
                                   const float* __restrict__ it,
                                   float* __restrict__ cur,
                                   float* __restrict__ acc,
                                   int n4u, int n4total) {
    int stride = gridDim.x * blockDim.x;
    for (int i = blockIdx.x * blockDim.x + threadIdx.x; i < n4total; i += stride) {
        float4 v = (i < n4u) ? ((const float4*)u)[i]
                             : ((const float4*)it)[i - n4u];
        ((float4*)cur)[i] = v;
        ((float4*)acc)[i] = v;
    }
}

__global__ void spmm_atomic_kernel(const int*   __restrict__ row,
                                   const int*   __restrict__ col,
                                   const float* __restrict__ val,
                                   const float* __restrict__ x,
                                   float*       __restrict__ y) {
    const int total = N_EDGES * 16;
    int stride = gridDim.x * blockDim.x;
    for (int t = blockIdx.x * blockDim.x + threadIdx.x; t < total; t += stride) {
        int e = t >> 4;
        int q = t & 15;
        int r = row[e];
        int c = col[e];
        float v = val[e];
        float4 g = ((const float4*)x)[c * 16 + q];
        float* yp = y + r * 64 + q * 4;
        atomicAdd(yp + 0, g.x * v);
        atomicAdd(yp + 1, g.y * v);
        atomicAdd(yp + 2, g.z * v);
        atomicAdd(yp + 3, g.w * v);
    }
}

__global__ void acc_add_kernel(float* __restrict__ acc,
                               const float* __restrict__ add,
                               int n4) {
    int stride = gridDim.x * blockDim.x;
    for (int i = blockIdx.x * blockDim.x + threadIdx.x; i < n4; i += stride) {
        float4 a = ((const float4*)acc)[i];
        float4 b = ((const float4*)add)[i];
        a.x += b.x; a.y += b.y; a.z += b.z; a.w += b.w;
        ((float4*)acc)[i] = a;
    }
}

extern "C" void kernel_launch(void* const* d_in, const int* in_sizes, int n_in,
                              void* d_out, int out_size, void* d_ws, size_t ws_size,
                              hipStream_t stream) {
    const float* uEmb = (const float*)d_in[0];
    const float* iEmb = (const float*)d_in[1];
    const int*   row  = (const int*)  d_in[2];
    const int*   col  = (const int*)  d_in[3];
    const float* val  = (const float*)d_in[4];

    float* acc = (float*)d_out;

    const int n4total = N_NODES * (LATDIM / 4);       // 4.8M groups of 4
    const int n4u     = USER_N  * (LATDIM / 4);
    const size_t embBytes  = (size_t)N_NODES * LATDIM * sizeof(float);
    const size_t embBytesH = (size_t)N_NODES * LATDIM * 2;   // 38.4MB

    const int BLK = 256;
    const int GRID_MEM = 2048;

    // ---- workspace layout ----
    auto align256 = [](size_t x) { return (x + 255) & ~(size_t)255; };
    size_t off = 0;
    size_t o_cur0   = off; off += align256(embBytesH);
    size_t o_c1     = off; off += align256(embBytesH);   // tempA = c1+c2
    size_t o_c2     = off; off += align256(embBytesH);
    size_t o_cvc    = off; off += align256((size_t)N_EDGES * 4);
    size_t o_cvv    = off; off += align256((size_t)N_EDGES * 2);
    size_t o_rowptr = off; off += align256(((size_t)N_NODES + 1) * 4);
    size_t o_craw   = off; off += align256((size_t)NCOARSE * NCHUNKS * 4);
    size_t o_cscan  = off; off += align256((size_t)NCOARSE * NCHUNKS * 4);
    size_t o_btot   = off; off += align256((size_t)NCOARSE * 4);
    size_t o_cbase  = off; off += align256(((size_t)NCOARSE + 1) * 4);
    size_t needed = off;

    char* wsb = (char*)d_ws;

    if (ws_size >= needed) {
        // ============ deterministic counting-sort CSR path ============
        ushort4* cur0 = (ushort4*)(wsb + o_cur0);
        ushort2* c1   = (ushort2*)(wsb + o_c1);
        ushort2* c2   = (ushort2*)(wsb + o_c2);
        int*  cvc     = (int*)(wsb + o_cvc);
        unsigned short* cvv = (unsigned short*)(wsb + o_cvv);
        int2* tempA   = (int2*)(wsb + o_c1);     // aliases c1+c2, dead after passB
        int* rowPtr   = (int*)(wsb + o_rowptr);
        int* cntRaw   = (int*)(wsb + o_craw);
        int* cntScan  = (int*)(wsb + o_cscan);
        int* btot     = (int*)(wsb + o_btot);
        int* cbase    = (int*)(wsb + o_cbase);

        cvt_concat_kernel<<<GRID_MEM, BLK, 0, stream>>>(uEmb, iEmb, cur0,
                                                        n4u, n4total);

        p1_hist_kernel      <<<GP1, 256, 0, stream>>>(row, cntRaw);
        p2_scanchunks_kernel<<<NCOARSE, 1024, 0, stream>>>(cntRaw, cntScan, btot);
        p3_scancoarse_kernel<<<1, 256, 0, stream>>>(btot, cbase, rowPtr);
        p4_scatter_kernel   <<<GP4, 256, 0, stream>>>(row, col, val, cntRaw,
                                                      cntScan, cbase, tempA);
        passB_kernel        <<<NCOARSE, 1024, 0, stream>>>(cbase, tempA,
                                                           cvc, cvv, rowPtr);

        const int GRID_SPMM = (N_NODES * 32 + BLK - 1) / BLK;   // 37500
        spmm_bf16_kernel<<<GRID_SPMM, BLK, 0, stream>>>(
            rowPtr, cvc, cvv, (const ushort2*)cur0, c1);
        spmm_bf16_kernel<<<GRID_SPMM, BLK, 0, stream>>>(
            rowPtr, cvc, cvv, (const ushort2*)c1, c2);
        spmm_bf16_final_kernel<<<GRID_SPMM, BLK, 0, stream>>>(
            rowPtr, cvc, cvv, (const ushort2*)c2, (const ushort2*)c1,
            (const float2*)uEmb, (const float2*)iEmb, (float2*)acc);
    } else {
        // ============ fallback: fp32 atomic path ============
        float* cur = (float*)wsb;
        float* nxt = (float*)(wsb + embBytes);
        copy_concat_kernel<<<GRID_MEM, BLK, 0, stream>>>(uEmb, iEmb, cur, acc,
                                                         n4u, n4total);
        for (int l = 0; l < N_LAYERS; ++l) {
            hipMemsetAsync(nxt, 0, embBytes, stream);
            spmm_atomic_kernel<<<4096, BLK, 0, stream>>>(row, col, val, cur, nxt);
            acc_add_kernel<<<GRID_MEM, BLK, 0, stream>>>(acc, nxt, n4total);
            float* t = cur; cur = nxt; nxt = t;
        }
    }
}

// Round 13
// 842.991 us; speedup vs baseline: 1.1027x; 1.1027x over previous
//
#include <hip/hip_runtime.h>
#include <hip/hip_bf16.h>

#define USER_N   100000
#define ITEM_N   200000
#define N_NODES  300000           // USER_N + ITEM_N
#define LATDIM   64
#define N_EDGES  9600000
#define N_LAYERS 3

// coarse bucket = row >> 11  (2048 rows ~= 523KB colval region)
#define CSHIFT   11
#define CROWS    2048
#define NCOARSE  ((N_NODES + CROWS - 1) / CROWS)   // 147
#define CHUNK    4096
#define NCHUNKS  ((N_EDGES + CHUNK - 1) / CHUNK)    // 2344
#define GP1      1024                               // p1 grid
#define GP4      1024                               // p4 grid (4 blocks/CU at 39KB)

// ---- bf16 helpers (RNE) ----
__device__ __forceinline__ unsigned short f2bf(float f) {
    unsigned int u = __float_as_uint(f);
    u += 0x7FFFu + ((u >> 16) & 1u);
    return (unsigned short)(u >> 16);
}
__device__ __forceinline__ float bf2f(unsigned short h) {
    return __uint_as_float(((unsigned int)h) << 16);
}

// ---------------------------------------------------------------------------
// convert concat(u,i) fp32 -> bf16 cur0
// ---------------------------------------------------------------------------
__global__ void cvt_concat_kernel(const float* __restrict__ u,
                                  const float* __restrict__ it,
                                  ushort4* __restrict__ cur0,
                                  int n4u, int n4total) {
    int stride = gridDim.x * blockDim.x;
    for (int i = blockIdx.x * blockDim.x + threadIdx.x; i < n4total; i += stride) {
        float4 v = (i < n4u) ? ((const float4*)u)[i]
                             : ((const float4*)it)[i - n4u];
        ushort4 o;
        o.x = f2bf(v.x); o.y = f2bf(v.y); o.z = f2bf(v.z); o.w = f2bf(v.w);
        cur0[i] = o;
    }
}

// ---------------------------------------------------------------------------
// p1: per-chunk coarse histogram -> cntRaw[bucket * NCHUNKS + chunk]
// (LDS atomics only — per-edge global atomics write through to HBM)
// ---------------------------------------------------------------------------
__global__ __launch_bounds__(256)
void p1_hist_kernel(const int* __restrict__ row, int* __restrict__ cntRaw) {
    __shared__ int h[NCOARSE];
    int t = threadIdx.x;
    for (int k = blockIdx.x; k < NCHUNKS; k += gridDim.x) {
        for (int i = t; i < NCOARSE; i += 256) h[i] = 0;
        __syncthreads();
        int e0 = k * CHUNK;
        int e1 = e0 + CHUNK; if (e1 > N_EDGES) e1 = N_EDGES;
        for (int e = e0 + t; e < e1; e += 256)
            atomicAdd(&h[row[e] >> CSHIFT], 1);
        __syncthreads();
        for (int i = t; i < NCOARSE; i += 256)
            cntRaw[i * NCHUNKS + k] = h[i];
        __syncthreads();
    }
}

// ---------------------------------------------------------------------------
// p2: per-bucket exclusive scan over its NCHUNKS counts -> cntScan (relative),
// bucket total -> btot.  One 1024-thread block per bucket; 3 elems/thread.
// ---------------------------------------------------------------------------
__global__ __launch_bounds__(1024)
void p2_scanchunks_kernel(const int* __restrict__ cntRaw,
                          int* __restrict__ cntScan,
                          int* __restrict__ btot) {
    __shared__ int lds[1024];
    int b = blockIdx.x, t = threadIdx.x;
    const int base = t * 3;
    int v0 = 0, v1 = 0, v2 = 0;
    if (base     < NCHUNKS) v0 = cntRaw[b * NCHUNKS + base];
    if (base + 1 < NCHUNKS) v1 = cntRaw[b * NCHUNKS + base + 1];
    if (base + 2 < NCHUNKS) v2 = cntRaw[b * NCHUNKS + base + 2];
    int s = v0 + v1 + v2;
    lds[t] = s;
    __syncthreads();
    for (int off = 1; off < 1024; off <<= 1) {
        int add = (t >= off) ? lds[t - off] : 0;
        __syncthreads();
        lds[t] += add;
        __syncthreads();
    }
    int ex = lds[t] - s;
    if (base     < NCHUNKS) cntScan[b * NCHUNKS + base]     = ex;
    if (base + 1 < NCHUNKS) cntScan[b * NCHUNKS + base + 1] = ex + v0;
    if (base + 2 < NCHUNKS) cntScan[b * NCHUNKS + base + 2] = ex + v0 + v1;
    if (t == 1023) btot[b] = lds[1023];
}

// ---------------------------------------------------------------------------
// p3: exclusive scan of NCOARSE totals -> cbase; rowPtr[N]=E
// ---------------------------------------------------------------------------
__global__ void p3_scancoarse_kernel(const int* __restrict__ btot,
                                     int* __restrict__ cbase,
                                     int* __restrict__ rowPtr) {
    __shared__ int lds[256];
    int t = threadIdx.x;
    int v = (t < NCOARSE) ? btot[t] : 0;
    lds[t] = v;
    __syncthreads();
    for (int off = 1; off < 256; off <<= 1) {
        int add = (t >= off) ? lds[t - off] : 0;
        __syncthreads();
        lds[t] += add;
        __syncthreads();
    }
    if (t < NCOARSE) cbase[t] = lds[t] - v;
    if (t == NCOARSE - 1) cbase[NCOARSE] = lds[t];
    if (t == 0) rowPtr[N_NODES] = N_EDGES;
}

// ---------------------------------------------------------------------------
// p4: chunked coarse partition with COALESCED run flush. Entries placed in an
// LDS stage at within-chunk sorted positions (LDS cursors); flush resolves
// each slot's bucket via a 4KB byte-map; dst = gcur[c] + (j - loff[c]).
// No global atomics.  key = row_local(11b)<<19 | col(19b)
// ---------------------------------------------------------------------------
__global__ __launch_bounds__(256)
void p4_scatter_kernel(const int*   __restrict__ row,
                       const int*   __restrict__ col,
                       const float* __restrict__ val,
                       const int*   __restrict__ cntRaw,
                       const int*   __restrict__ cntScan,
                       const int*   __restrict__ cbase,
                       int2*        __restrict__ tempA) {
    __shared__ int2 stage[CHUNK];               // 32 KB
    __shared__ unsigned char bmap[CHUNK];       // 4 KB
    __shared__ int  loff[NCOARSE];
    __shared__ int  lcur[NCOARSE];
    __shared__ int  gcur[NCOARSE];
    __shared__ int  sc[256];
    int t = threadIdx.x;
    for (int k = blockIdx.x; k < NCHUNKS; k += gridDim.x) {
        int hv = 0;
        if (t < NCOARSE) {
            hv = cntRaw[t * NCHUNKS + k];
            gcur[t] = cbase[t] + cntScan[t * NCHUNKS + k];
        }
        sc[t] = hv;
        __syncthreads();
        for (int off = 1; off < 256; off <<= 1) {
            int add = (t >= off) ? sc[t - off] : 0;
            __syncthreads();
            sc[t] += add;
            __syncthreads();
        }
        int exl = sc[t] - hv;
        if (t < NCOARSE) {
            loff[t] = exl;
            lcur[t] = exl;
        }
        __syncthreads();
        if (t < NCOARSE) {                      // fill bucket byte-map
            int e = exl + hv;
            for (int j = exl; j < e; ++j) bmap[j] = (unsigned char)t;
        }
        int e0 = k * CHUNK;
        int e1 = e0 + CHUNK; if (e1 > N_EDGES) e1 = N_EDGES;
        int n = e1 - e0;
        for (int e = e0 + t; e < e1; e += 256) {
            int r = row[e];
            int c = r >> CSHIFT;
            int p = atomicAdd(&lcur[c], 1);
            stage[p] = make_int2(((r & (CROWS - 1)) << 19) | col[e],
                                 __float_as_int(val[e]));
        }
        __syncthreads();
        for (int j = t; j < n; j += 256) {      // coalesced run flush
            int c = bmap[j];
            tempA[gcur[c] + (j - loff[c])] = stage[j];
        }
        __syncthreads();
    }
}

// ---------------------------------------------------------------------------
// passB: one 1024-thread block per coarse bucket. LDS hist of 2048 rows,
// LDS scan (emits rowPtr slice), LDS-cursor scatter into the bucket's
// exclusive ~523KB colval region. SINGLE 8B int2 store per edge (merges in
// L2 — split 4B/2B streams amplified 9x, R11).  colval = {col*32, fp32 val}.
// ---------------------------------------------------------------------------
__global__ __launch_bounds__(1024)
void passB_kernel(const int*  __restrict__ cbase,
                  const int2* __restrict__ tempA,
                  int2*       __restrict__ colval,
                  int*        __restrict__ rowPtr) {
    __shared__ int hist[CROWS];     // 8 KB
    __shared__ int psum[1024];      // 4 KB
    __shared__ int curs[CROWS];     // 8 KB
    int c = blockIdx.x;
    int t = threadIdx.x;
    int beg = cbase[c], end = cbase[c + 1];

    hist[t] = 0; hist[t + 1024] = 0;
    __syncthreads();
    for (int i = beg + t; i < end; i += 1024)
        atomicAdd(&hist[((unsigned)tempA[i].x) >> 19], 1);
    __syncthreads();

    int b0 = hist[2 * t], b1 = hist[2 * t + 1];
    int tot = b0 + b1;
    psum[t] = tot;
    __syncthreads();
    for (int off = 1; off < 1024; off <<= 1) {
        int add = (t >= off) ? psum[t - off] : 0;
        __syncthreads();
        psum[t] += add;
        __syncthreads();
    }
    int ex = psum[t] - tot;              // exclusive over pairs
    int j0 = 2 * t, j1 = 2 * t + 1;
    int e0 = beg + ex, e1 = beg + ex + b0;
    curs[j0] = e0;
    curs[j1] = e1;
    int gr0 = c * CROWS + j0;
    int gr1 = c * CROWS + j1;
    if (gr0 < N_NODES) rowPtr[gr0] = e0;
    if (gr1 < N_NODES) rowPtr[gr1] = e1;
    __syncthreads();

    for (int i = beg + t; i < end; i += 1024) {
        int2 kv = tempA[i];
        int rl = ((unsigned)kv.x) >> 19;
        int pos = atomicAdd(&curs[rl], 1);
        colval[pos] = make_int2((kv.x & 0x7FFFF) << 5, kv.y);   // col*32, f32 val
    }
}

// ---------------------------------------------------------------------------
// bf16 CSR SpMM: 32 lanes/row, lane q owns dims [2q,2q+2) (ushort2 gather,
// full 128B line per edge; E[max deg of 2 rows/wave] beats 4 rows/wave).
// 8 gathers in flight. colval.x pre-scaled col*32, colval.y fp32 val.
// ---------------------------------------------------------------------------
__global__ void spmm_bf16_kernel(const int*  __restrict__ rp,
                                 const int2* __restrict__ cv,
                                 const ushort2* __restrict__ x2,
                                 ushort2*       __restrict__ y2) {
    int g = (blockIdx.x * blockDim.x + threadIdx.x) >> 5;   // row
    if (g >= N_NODES) return;
    int q = threadIdx.x & 31;
    int beg = rp[g];
    int end = rp[g + 1];
    const ushort2* xq = x2 + q;

    float s0 = 0.f, s1 = 0.f;
    int i = beg;
    for (; i + 8 <= end; i += 8) {
        int2 cc[8]; ushort2 gg[8];
        #pragma unroll
        for (int k = 0; k < 8; ++k) cc[k] = cv[i + k];
        #pragma unroll
        for (int k = 0; k < 8; ++k) gg[k] = xq[cc[k].x];
        #pragma unroll
        for (int k = 0; k < 8; ++k) {
            float v = __int_as_float(cc[k].y);
            s0 += bf2f(gg[k].x) * v; s1 += bf2f(gg[k].y) * v;
        }
    }
    for (; i < end; ++i) {
        int2 cc = cv[i];
        ushort2 gg = xq[cc.x];
        float v = __int_as_float(cc.y);
        s0 += bf2f(gg.x) * v; s1 += bf2f(gg.y) * v;
    }

    ushort2 o;
    o.x = f2bf(s0); o.y = f2bf(s1);
    y2[(size_t)g * 32 + q] = o;
}

// ---------------------------------------------------------------------------
// fused layer-3 SpMM + final accumulation:
// acc[g] = emb[g] + c1[g] + c2[g] + (A @ c2)[g]    (fp32 out)
// ---------------------------------------------------------------------------
__global__ void spmm_bf16_final_kernel(const int*  __restrict__ rp,
                                       const int2* __restrict__ cv,
                                       const ushort2* __restrict__ x2,   // c2
                                       const ushort2* __restrict__ c1,
                                       const float2*  __restrict__ u2,
                                       const float2*  __restrict__ i2,
                                       float2*        __restrict__ acc2) {
    int g = (blockIdx.x * blockDim.x + threadIdx.x) >> 5;   // row
    if (g >= N_NODES) return;
    int q = threadIdx.x & 31;
    int beg = rp[g];
    int end = rp[g + 1];
    const ushort2* xq = x2 + q;

    float s0 = 0.f, s1 = 0.f;
    int i = beg;
    for (; i + 8 <= end; i += 8) {
        int2 cc[8]; ushort2 gg[8];
        #pragma unroll
        for (int k = 0; k < 8; ++k) cc[k] = cv[i + k];
        #pragma unroll
        for (int k = 0; k < 8; ++k) gg[k] = xq[cc[k].x];
        #pragma unroll
        for (int k = 0; k < 8; ++k) {
            float v = __int_as_float(cc[k].y);
            s0 += bf2f(gg[k].x) * v; s1 += bf2f(gg[k].y) * v;
        }
    }
    for (; i < end; ++i) {
        int2 cc = cv[i];
        ushort2 gg = xq[cc.x];
        float v = __int_as_float(cc.y);
        s0 += bf2f(gg.x) * v; s1 += bf2f(gg.y) * v;
    }

    size_t o = (size_t)g * 32 + q;
    float2 e = (g < USER_N) ? u2[o] : i2[o - (size_t)USER_N * 32];
    ushort2 a = c1[o];
    ushort2 b = x2[o];           // c2 own-row
    float2 r;
    r.x = e.x + bf2f(a.x) + bf2f(b.x) + s0;
    r.y = e.y + bf2f(a.y) + bf2f(b.y) + s1;
    acc2[o] = r;
}

// ---------------------------------------------------------------------------
// Fallback path: fp32 COO atomic SpMM + acc add (used if ws too small)
// ---------------------------------------------------------------------------
__global__ void copy_concat_kernel(const float* __restrict__ u,
                                   const float* __restrict__ it,
                                   float* __restrict__ cur,
                                   float* __restrict__ acc,
                                   int n4u, int n4total) {
    int stride = gridDim.x * blockDim.x;
    for (int i = blockIdx.x * blockDim.x + threadIdx.x; i < n4total; i += stride) {
        float4 v = (i < n4u) ? ((const float4*)u)[i]
                             : ((const float4*)it)[i - n4u];
        ((float4*)cur)[i] = v;
        ((float4*)acc)[i] = v;
    }
}

__global__ void spmm_atomic_kernel(const int*   __restrict__ row,
                                   const int*   __restrict__ col,
                                   const float* __restrict__ val,
                                   const float* __restrict__ x,
                                   float*       __restrict__ y) {
    const int total = N_EDGES * 16;
    int stride = gridDim.x * blockDim.x;
    for (int t = blockIdx.x * blockDim.x + threadIdx.x; t < total; t += stride) {
        int e = t >> 4;
        int q = t & 15;
        int r = row[e];
        int c = col[e];
        float v = val[e];
        float4 g = ((const float4*)x)[c * 16 + q];
        float* yp = y + r * 64 + q * 4;
        atomicAdd(yp + 0, g.x * v);
        atomicAdd(yp + 1, g.y * v);
        atomicAdd(yp + 2, g.z * v);
        atomicAdd(yp + 3, g.w * v);
    }
}

__global__ void acc_add_kernel(float* __restrict__ acc,
                               const float* __restrict__ add,
                               int n4) {
    int stride = gridDim.x * blockDim.x;
    for (int i = blockIdx.x * blockDim.x + threadIdx.x; i < n4; i += stride) {
        float4 a = ((const float4*)acc)[i];
        float4 b = ((const float4*)add)[i];
        a.x += b.x; a.y += b.y; a.z += b.z; a.w += b.w;
        ((float4*)acc)[i] = a;
    }
}

extern "C" void kernel_launch(void* const* d_in, const int* in_sizes, int n_in,
                              void* d_out, int out_size, void* d_ws, size_t ws_size,
                              hipStream_t stream) {
    const float* uEmb = (const float*)d_in[0];
    const float* iEmb = (const float*)d_in[1];
    const int*   row  = (const int*)  d_in[2];
    const int*   col  = (const int*)  d_in[3];
    const float* val  = (const float*)d_in[4];

    float* acc = (float*)d_out;

    const int n4total = N_NODES * (LATDIM / 4);       // 4.8M groups of 4
    const int n4u     = USER_N  * (LATDIM / 4);
    const size_t embBytes  = (size_t)N_NODES * LATDIM * sizeof(float);
    const size_t embBytesH = (size_t)N_NODES * LATDIM * 2;   // 38.4MB

    const int BLK = 256;
    const int GRID_MEM = 2048;

    // ---- workspace layout ----
    auto align256 = [](size_t x) { return (x + 255) & ~(size_t)255; };
    size_t off = 0;
    size_t o_cur0   = off; off += align256(embBytesH);
    size_t o_c1     = off; off += align256(embBytesH);   // tempA = c1+c2
    size_t o_c2     = off; off += align256(embBytesH);
    size_t o_colval = off; off += align256((size_t)N_EDGES * 8);
    size_t o_rowptr = off; off += align256(((size_t)N_NODES + 1) * 4);
    size_t o_craw   = off; off += align256((size_t)NCOARSE * NCHUNKS * 4);
    size_t o_cscan  = off; off += align256((size_t)NCOARSE * NCHUNKS * 4);
    size_t o_btot   = off; off += align256((size_t)NCOARSE * 4);
    size_t o_cbase  = off; off += align256(((size_t)NCOARSE + 1) * 4);
    size_t needed = off;

    char* wsb = (char*)d_ws;

    if (ws_size >= needed) {
        // ============ deterministic counting-sort CSR path ============
        ushort4* cur0 = (ushort4*)(wsb + o_cur0);
        ushort2* c1   = (ushort2*)(wsb + o_c1);
        ushort2* c2   = (ushort2*)(wsb + o_c2);
        int2* colval  = (int2*)(wsb + o_colval);
        int2* tempA   = (int2*)(wsb + o_c1);     // aliases c1+c2, dead after passB
        int* rowPtr   = (int*)(wsb + o_rowptr);
        int* cntRaw   = (int*)(wsb + o_craw);
        int* cntScan  = (int*)(wsb + o_cscan);
        int* btot     = (int*)(wsb + o_btot);
        int* cbase    = (int*)(wsb + o_cbase);

        cvt_concat_kernel<<<GRID_MEM, BLK, 0, stream>>>(uEmb, iEmb, cur0,
                                                        n4u, n4total);

        p1_hist_kernel      <<<GP1, 256, 0, stream>>>(row, cntRaw);
        p2_scanchunks_kernel<<<NCOARSE, 1024, 0, stream>>>(cntRaw, cntScan, btot);
        p3_scancoarse_kernel<<<1, 256, 0, stream>>>(btot, cbase, rowPtr);
        p4_scatter_kernel   <<<GP4, 256, 0, stream>>>(row, col, val, cntRaw,
                                                      cntScan, cbase, tempA);
        passB_kernel        <<<NCOARSE, 1024, 0, stream>>>(cbase, tempA,
                                                           colval, rowPtr);

        const int GRID_SPMM = (N_NODES * 32 + BLK - 1) / BLK;   // 37500
        spmm_bf16_kernel<<<GRID_SPMM, BLK, 0, stream>>>(
            rowPtr, colval, (const ushort2*)cur0, c1);
        spmm_bf16_kernel<<<GRID_SPMM, BLK, 0, stream>>>(
            rowPtr, colval, (const ushort2*)c1, c2);
        spmm_bf16_final_kernel<<<GRID_SPMM, BLK, 0, stream>>>(
            rowPtr, colval, (const ushort2*)c2, (const ushort2*)c1,
            (const float2*)uEmb, (const float2*)iEmb, (float2*)acc);
    } else {
        // ============ fallback: fp32 atomic path ============
        float* cur = (float*)wsb;
        float* nxt = (float*)(wsb + embBytes);
        copy_concat_kernel<<<GRID_MEM, BLK, 0, stream>>>(uEmb, iEmb, cur, acc,
                                                         n4u, n4total);
        for (int l = 0; l < N_LAYERS; ++l) {
            hipMemsetAsync(nxt, 0, embBytes, stream);
            spmm_atomic_kernel<<<4096, BLK, 0, stream>>>(row, col, val, cur, nxt);
            acc_add_kernel<<<GRID_MEM, BLK, 0, stream>>>(acc, nxt, n4total);
            float* t = cur; cur = nxt; nxt = t;
        }
    }
}

// Round 14
// 831.429 us; speedup vs baseline: 1.1180x; 1.0139x over previous
//
#include <hip/hip_runtime.h>
#include <hip/hip_bf16.h>

#define USER_N   100000
#define ITEM_N   200000
#define N_NODES  300000           // USER_N + ITEM_N
#define LATDIM   64
#define N_EDGES  9600000
#define N_LAYERS 3

// coarse bucket = row >> 11  (2048 rows ~= 523KB colval region)
#define CSHIFT   11
#define CROWS    2048
#define NCOARSE  ((N_NODES + CROWS - 1) / CROWS)   // 147
#define CHUNK    4096
#define NCHUNKS  ((N_EDGES + CHUNK - 1) / CHUNK)    // 2344
#define GP1      1024                               // p1 grid
#define GP4      1024                               // p4 grid

// ---- bf16 helpers (RNE) ----
__device__ __forceinline__ unsigned short f2bf(float f) {
    unsigned int u = __float_as_uint(f);
    u += 0x7FFFu + ((u >> 16) & 1u);
    return (unsigned short)(u >> 16);
}
__device__ __forceinline__ float bf2f(unsigned short h) {
    return __uint_as_float(((unsigned int)h) << 16);
}

// ---------------------------------------------------------------------------
// convert concat(u,i) fp32 -> bf16 cur0
// ---------------------------------------------------------------------------
__global__ void cvt_concat_kernel(const float* __restrict__ u,
                                  const float* __restrict__ it,
                                  ushort4* __restrict__ cur0,
                                  int n4u, int n4total) {
    int stride = gridDim.x * blockDim.x;
    for (int i = blockIdx.x * blockDim.x + threadIdx.x; i < n4total; i += stride) {
        float4 v = (i < n4u) ? ((const float4*)u)[i]
                             : ((const float4*)it)[i - n4u];
        ushort4 o;
        o.x = f2bf(v.x); o.y = f2bf(v.y); o.z = f2bf(v.z); o.w = f2bf(v.w);
        cur0[i] = o;
    }
}

// ---------------------------------------------------------------------------
// p1: per-chunk coarse histogram -> cntRaw[bucket * NCHUNKS + chunk]
// (LDS atomics only — per-edge global atomics write through to HBM)
// ---------------------------------------------------------------------------
__global__ __launch_bounds__(256)
void p1_hist_kernel(const int* __restrict__ row, int* __restrict__ cntRaw) {
    __shared__ int h[NCOARSE];
    int t = threadIdx.x;
    for (int k = blockIdx.x; k < NCHUNKS; k += gridDim.x) {
        for (int i = t; i < NCOARSE; i += 256) h[i] = 0;
        __syncthreads();
        int e0 = k * CHUNK;
        int e1 = e0 + CHUNK; if (e1 > N_EDGES) e1 = N_EDGES;
        for (int e = e0 + t; e < e1; e += 256)
            atomicAdd(&h[row[e] >> CSHIFT], 1);
        __syncthreads();
        for (int i = t; i < NCOARSE; i += 256)
            cntRaw[i * NCHUNKS + k] = h[i];
        __syncthreads();
    }
}

// ---------------------------------------------------------------------------
// p2: per-bucket exclusive scan over its NCHUNKS counts -> cntScan (relative),
// bucket total -> btot.  One 1024-thread block per bucket; 3 elems/thread.
// ---------------------------------------------------------------------------
__global__ __launch_bounds__(1024)
void p2_scanchunks_kernel(const int* __restrict__ cntRaw,
                          int* __restrict__ cntScan,
                          int* __restrict__ btot) {
    __shared__ int lds[1024];
    int b = blockIdx.x, t = threadIdx.x;
    const int base = t * 3;
    int v0 = 0, v1 = 0, v2 = 0;
    if (base     < NCHUNKS) v0 = cntRaw[b * NCHUNKS + base];
    if (base + 1 < NCHUNKS) v1 = cntRaw[b * NCHUNKS + base + 1];
    if (base + 2 < NCHUNKS) v2 = cntRaw[b * NCHUNKS + base + 2];
    int s = v0 + v1 + v2;
    lds[t] = s;
    __syncthreads();
    for (int off = 1; off < 1024; off <<= 1) {
        int add = (t >= off) ? lds[t - off] : 0;
        __syncthreads();
        lds[t] += add;
        __syncthreads();
    }
    int ex = lds[t] - s;
    if (base     < NCHUNKS) cntScan[b * NCHUNKS + base]     = ex;
    if (base + 1 < NCHUNKS) cntScan[b * NCHUNKS + base + 1] = ex + v0;
    if (base + 2 < NCHUNKS) cntScan[b * NCHUNKS + base + 2] = ex + v0 + v1;
    if (t == 1023) btot[b] = lds[1023];
}

// ---------------------------------------------------------------------------
// p3: exclusive scan of NCOARSE totals -> cbase; rowPtr[N]=E
// ---------------------------------------------------------------------------
__global__ void p3_scancoarse_kernel(const int* __restrict__ btot,
                                     int* __restrict__ cbase,
                                     int* __restrict__ rowPtr) {
    __shared__ int lds[256];
    int t = threadIdx.x;
    int v = (t < NCOARSE) ? btot[t] : 0;
    lds[t] = v;
    __syncthreads();
    for (int off = 1; off < 256; off <<= 1) {
        int add = (t >= off) ? lds[t - off] : 0;
        __syncthreads();
        lds[t] += add;
        __syncthreads();
    }
    if (t < NCOARSE) cbase[t] = lds[t] - v;
    if (t == NCOARSE - 1) cbase[NCOARSE] = lds[t];
    if (t == 0) rowPtr[N_NODES] = N_EDGES;
}

// ---------------------------------------------------------------------------
// p4: chunked coarse partition with COALESCED run flush. Entries placed in an
// LDS stage at within-chunk sorted positions (LDS cursors); flush resolves
// each slot's bucket via a 4KB byte-map; dst = gcur[c] + (j - loff[c]).
// No global atomics.  key = row_local(11b)<<19 | col(19b)
// ---------------------------------------------------------------------------
__global__ __launch_bounds__(256)
void p4_scatter_kernel(const int*   __restrict__ row,
                       const int*   __restrict__ col,
                       const float* __restrict__ val,
                       const int*   __restrict__ cntRaw,
                       const int*   __restrict__ cntScan,
                       const int*   __restrict__ cbase,
                       int2*        __restrict__ tempA) {
    __shared__ int2 stage[CHUNK];               // 32 KB
    __shared__ unsigned char bmap[CHUNK];       // 4 KB
    __shared__ int  loff[NCOARSE];
    __shared__ int  lcur[NCOARSE];
    __shared__ int  gcur[NCOARSE];
    __shared__ int  sc[256];
    int t = threadIdx.x;
    for (int k = blockIdx.x; k < NCHUNKS; k += gridDim.x) {
        int hv = 0;
        if (t < NCOARSE) {
            hv = cntRaw[t * NCHUNKS + k];
            gcur[t] = cbase[t] + cntScan[t * NCHUNKS + k];
        }
        sc[t] = hv;
        __syncthreads();
        for (int off = 1; off < 256; off <<= 1) {
            int add = (t >= off) ? sc[t - off] : 0;
            __syncthreads();
            sc[t] += add;
            __syncthreads();
        }
        int exl = sc[t] - hv;
        if (t < NCOARSE) {
            loff[t] = exl;
            lcur[t] = exl;
        }
        __syncthreads();
        if (t < NCOARSE) {                      // fill bucket byte-map
            int e = exl + hv;
            for (int j = exl; j < e; ++j) bmap[j] = (unsigned char)t;
        }
        int e0 = k * CHUNK;
        int e1 = e0 + CHUNK; if (e1 > N_EDGES) e1 = N_EDGES;
        int n = e1 - e0;
        for (int e = e0 + t; e < e1; e += 256) {
            int r = row[e];
            int c = r >> CSHIFT;
            int p = atomicAdd(&lcur[c], 1);
            stage[p] = make_int2(((r & (CROWS - 1)) << 19) | col[e],
                                 __float_as_int(val[e]));
        }
        __syncthreads();
        for (int j = t; j < n; j += 256) {      // coalesced run flush
            int c = bmap[j];
            tempA[gcur[c] + (j - loff[c])] = stage[j];
        }
        __syncthreads();
    }
}

// ---------------------------------------------------------------------------
// passB: one 1024-thread block per coarse bucket. LDS hist of 2048 rows,
// LDS scan (emits rowPtr slice), LDS-cursor scatter into the bucket's
// exclusive ~523KB colval region. SINGLE 8B int2 store per edge (merges in
// L2 — split streams amplified 9x, R11).  colval = {col*16, fp32 val}:
// col*16 is the ushort4 index for the 16-lane final; 32-lane spmm shifts <<1.
// ---------------------------------------------------------------------------
__global__ __launch_bounds__(1024)
void passB_kernel(const int*  __restrict__ cbase,
                  const int2* __restrict__ tempA,
                  int2*       __restrict__ colval,
                  int*        __restrict__ rowPtr) {
    __shared__ int hist[CROWS];     // 8 KB
    __shared__ int psum[1024];      // 4 KB
    __shared__ int curs[CROWS];     // 8 KB
    int c = blockIdx.x;
    int t = threadIdx.x;
    int beg = cbase[c], end = cbase[c + 1];

    hist[t] = 0; hist[t + 1024] = 0;
    __syncthreads();
    for (int i = beg + t; i < end; i += 1024)
        atomicAdd(&hist[((unsigned)tempA[i].x) >> 19], 1);
    __syncthreads();

    int b0 = hist[2 * t], b1 = hist[2 * t + 1];
    int tot = b0 + b1;
    psum[t] = tot;
    __syncthreads();
    for (int off = 1; off < 1024; off <<= 1) {
        int add = (t >= off) ? psum[t - off] : 0;
        __syncthreads();
        psum[t] += add;
        __syncthreads();
    }
    int ex = psum[t] - tot;              // exclusive over pairs
    int j0 = 2 * t, j1 = 2 * t + 1;
    int e0 = beg + ex, e1 = beg + ex + b0;
    curs[j0] = e0;
    curs[j1] = e1;
    int gr0 = c * CROWS + j0;
    int gr1 = c * CROWS + j1;
    if (gr0 < N_NODES) rowPtr[gr0] = e0;
    if (gr1 < N_NODES) rowPtr[gr1] = e1;
    __syncthreads();

    for (int i = beg + t; i < end; i += 1024) {
        int2 kv = tempA[i];
        int rl = ((unsigned)kv.x) >> 19;
        int pos = atomicAdd(&curs[rl], 1);
        colval[pos] = make_int2((kv.x & 0x7FFFF) << 4, kv.y);   // col*16, f32 val
    }
}

// ---------------------------------------------------------------------------
// bf16 CSR SpMM: 32 lanes/row, lane q owns dims [2q,2q+2) (ushort2 gather,
// full 128B line per edge; best wave balance for the gather-only layers).
// 8 gathers in flight. colval.x = col*16, shifted <<1 for ushort2 indexing.
// ---------------------------------------------------------------------------
__global__ void spmm_bf16_kernel(const int*  __restrict__ rp,
                                 const int2* __restrict__ cv,
                                 const ushort2* __restrict__ x2,
                                 ushort2*       __restrict__ y2) {
    int g = (blockIdx.x * blockDim.x + threadIdx.x) >> 5;   // row
    if (g >= N_NODES) return;
    int q = threadIdx.x & 31;
    int beg = rp[g];
    int end = rp[g + 1];
    const ushort2* xq = x2 + q;

    float s0 = 0.f, s1 = 0.f;
    int i = beg;
    for (; i + 8 <= end; i += 8) {
        int2 cc[8]; ushort2 gg[8];
        #pragma unroll
        for (int k = 0; k < 8; ++k) cc[k] = cv[i + k];
        #pragma unroll
        for (int k = 0; k < 8; ++k) gg[k] = xq[cc[k].x << 1];
        #pragma unroll
        for (int k = 0; k < 8; ++k) {
            float v = __int_as_float(cc[k].y);
            s0 += bf2f(gg[k].x) * v; s1 += bf2f(gg[k].y) * v;
        }
    }
    for (; i < end; ++i) {
        int2 cc = cv[i];
        ushort2 gg = xq[cc.x << 1];
        float v = __int_as_float(cc.y);
        s0 += bf2f(gg.x) * v; s1 += bf2f(gg.y) * v;
    }

    ushort2 o;
    o.x = f2bf(s0); o.y = f2bf(s1);
    y2[(size_t)g * 32 + q] = o;
}

// ---------------------------------------------------------------------------
// fused layer-3 SpMM + final accumulation (16 lanes/row, ushort4 — the
// epilogue reads e/c1/c2 and writes fp32 acc, which favors 16B-per-lane):
// acc[g] = emb[g] + c1[g] + c2[g] + (A @ c2)[g]
// ---------------------------------------------------------------------------
__global__ void spmm_bf16_final_kernel(const int*  __restrict__ rp,
                                       const int2* __restrict__ cv,
                                       const ushort4* __restrict__ x4,   // c2
                                       const ushort4* __restrict__ c1,
                                       const float4*  __restrict__ u4,
                                       const float4*  __restrict__ i4,
                                       float4*        __restrict__ acc4) {
    int g = (blockIdx.x * blockDim.x + threadIdx.x) >> 4;   // row
    if (g >= N_NODES) return;
    int q = threadIdx.x & 15;
    int beg = rp[g];
    int end = rp[g + 1];
    const ushort4* xq = x4 + q;

    float s0 = 0.f, s1 = 0.f, s2 = 0.f, s3 = 0.f;
    int i = beg;
    for (; i + 8 <= end; i += 8) {
        int2 cc[8]; ushort4 gg[8];
        #pragma unroll
        for (int k = 0; k < 8; ++k) cc[k] = cv[i + k];
        #pragma unroll
        for (int k = 0; k < 8; ++k) gg[k] = xq[cc[k].x];
        #pragma unroll
        for (int k = 0; k < 8; ++k) {
            float v = __int_as_float(cc[k].y);
            s0 += bf2f(gg[k].x) * v; s1 += bf2f(gg[k].y) * v;
            s2 += bf2f(gg[k].z) * v; s3 += bf2f(gg[k].w) * v;
        }
    }
    for (; i < end; ++i) {
        int2 cc = cv[i];
        ushort4 gg = xq[cc.x];
        float v = __int_as_float(cc.y);
        s0 += bf2f(gg.x) * v; s1 += bf2f(gg.y) * v;
        s2 += bf2f(gg.z) * v; s3 += bf2f(gg.w) * v;
    }

    size_t o = (size_t)g * 16 + q;
    float4 e = (g < USER_N) ? u4[o] : i4[o - (size_t)USER_N * 16];
    ushort4 a = c1[o];
    ushort4 b = x4[o];           // c2 own-row
    float4 r;
    r.x = e.x + bf2f(a.x) + bf2f(b.x) + s0;
    r.y = e.y + bf2f(a.y) + bf2f(b.y) + s1;
    r.z = e.z + bf2f(a.z) + bf2f(b.z) + s2;
    r.w = e.w + bf2f(a.w) + bf2f(b.w) + s3;
    acc4[o] = r;
}

// ---------------------------------------------------------------------------
// Fallback path: fp32 COO atomic SpMM + acc add (used if ws too small)
// ---------------------------------------------------------------------------
__global__ void copy_concat_kernel(const float* __restrict__ u,
                                   const float* __restrict__ it,
                                   float* __restrict__ cur,
                                   float* __restrict__ acc,
                                   int n4u, int n4total) {
    int stride = gridDim.x * blockDim.x;
    for (int i = blockIdx.x * blockDim.x + threadIdx.x; i < n4total; i += stride) {
        float4 v = (i < n4u) ? ((const float4*)u)[i]
                             : ((const float4*)it)[i - n4u];
        ((float4*)cur)[i] = v;
        ((float4*)acc)[i] = v;
    }
}

__global__ void spmm_atomic_kernel(const int*   __restrict__ row,
                                   const int*   __restrict__ col,
                                   const float* __restrict__ val,
                                   const float* __restrict__ x,
                                   float*       __restrict__ y) {
    const int total = N_EDGES * 16;
    int stride = gridDim.x * blockDim.x;
    for (int t = blockIdx.x * blockDim.x + threadIdx.x; t < total; t += stride) {
        int e = t >> 4;
        int q = t & 15;
        int r = row[e];
        int c = col[e];
        float v = val[e];
        float4 g = ((const float4*)x)[c * 16 + q];
        float* yp = y + r * 64 + q * 4;
        atomicAdd(yp + 0, g.x * v);
        atomicAdd(yp + 1, g.y * v);
        atomicAdd(yp + 2, g.z * v);
        atomicAdd(yp + 3, g.w * v);
    }
}

__global__ void acc_add_kernel(float* __restrict__ acc,
                               const float* __restrict__ add,
                               int n4) {
    int stride = gridDim.x * blockDim.x;
    for (int i = blockIdx.x * blockDim.x + threadIdx.x; i < n4; i += stride) {
        float4 a = ((const float4*)acc)[i];
        float4 b = ((const float4*)add)[i];
        a.x += b.x; a.y += b.y; a.z += b.z; a.w += b.w;
        ((float4*)acc)[i] = a;
    }
}

extern "C" void kernel_launch(void* const* d_in, const int* in_sizes, int n_in,
                              void* d_out, int out_size, void* d_ws, size_t ws_size,
                              hipStream_t stream) {
    const float* uEmb = (const float*)d_in[0];
    const float* iEmb = (const float*)d_in[1];
    const int*   row  = (const int*)  d_in[2];
    const int*   col  = (const int*)  d_in[3];
    const float* val  = (const float*)d_in[4];

    float* acc = (float*)d_out;

    const int n4total = N_NODES * (LATDIM / 4);       // 4.8M groups of 4
    const int n4u     = USER_N  * (LATDIM / 4);
    const size_t embBytes  = (size_t)N_NODES * LATDIM * sizeof(float);
    const size_t embBytesH = (size_t)N_NODES * LATDIM * 2;   // 38.4MB

    const int BLK = 256;
    const int GRID_MEM = 2048;

    // ---- workspace layout ----
    auto align256 = [](size_t x) { return (x + 255) & ~(size_t)255; };
    size_t off = 0;
    size_t o_cur0   = off; off += align256(embBytesH);
    size_t o_c1     = off; off += align256(embBytesH);   // tempA = c1+c2
    size_t o_c2     = off; off += align256(embBytesH);
    size_t o_colval = off; off += align256((size_t)N_EDGES * 8);
    size_t o_rowptr = off; off += align256(((size_t)N_NODES + 1) * 4);
    size_t o_craw   = off; off += align256((size_t)NCOARSE * NCHUNKS * 4);
    size_t o_cscan  = off; off += align256((size_t)NCOARSE * NCHUNKS * 4);
    size_t o_btot   = off; off += align256((size_t)NCOARSE * 4);
    size_t o_cbase  = off; off += align256(((size_t)NCOARSE + 1) * 4);
    size_t needed = off;

    char* wsb = (char*)d_ws;

    if (ws_size >= needed) {
        // ============ deterministic counting-sort CSR path ============
        ushort4* cur0 = (ushort4*)(wsb + o_cur0);
        ushort4* c1   = (ushort4*)(wsb + o_c1);
        ushort4* c2   = (ushort4*)(wsb + o_c2);
        int2* colval  = (int2*)(wsb + o_colval);
        int2* tempA   = (int2*)(wsb + o_c1);     // aliases c1+c2, dead after passB
        int* rowPtr   = (int*)(wsb + o_rowptr);
        int* cntRaw   = (int*)(wsb + o_craw);
        int* cntScan  = (int*)(wsb + o_cscan);
        int* btot     = (int*)(wsb + o_btot);
        int* cbase    = (int*)(wsb + o_cbase);

        cvt_concat_kernel<<<GRID_MEM, BLK, 0, stream>>>(uEmb, iEmb, cur0,
                                                        n4u, n4total);

        p1_hist_kernel      <<<GP1, 256, 0, stream>>>(row, cntRaw);
        p2_scanchunks_kernel<<<NCOARSE, 1024, 0, stream>>>(cntRaw, cntScan, btot);
        p3_scancoarse_kernel<<<1, 256, 0, stream>>>(btot, cbase, rowPtr);
        p4_scatter_kernel   <<<GP4, 256, 0, stream>>>(row, col, val, cntRaw,
                                                      cntScan, cbase, tempA);
        passB_kernel        <<<NCOARSE, 1024, 0, stream>>>(cbase, tempA,
                                                           colval, rowPtr);

        const int GRID_SPMM32 = (N_NODES * 32 + BLK - 1) / BLK;   // 37500
        const int GRID_SPMM16 = (N_NODES * 16 + BLK - 1) / BLK;   // 18750
        spmm_bf16_kernel<<<GRID_SPMM32, BLK, 0, stream>>>(
            rowPtr, colval, (const ushort2*)cur0, (ushort2*)c1);
        spmm_bf16_kernel<<<GRID_SPMM32, BLK, 0, stream>>>(
            rowPtr, colval, (const ushort2*)c1, (ushort2*)c2);
        spmm_bf16_final_kernel<<<GRID_SPMM16, BLK, 0, stream>>>(
            rowPtr, colval, c2, c1,
            (const float4*)uEmb, (const float4*)iEmb, (float4*)acc);
    } else {
        // ============ fallback: fp32 atomic path ============
        float* cur = (float*)wsb;
        float* nxt = (float*)(wsb + embBytes);
        copy_concat_kernel<<<GRID_MEM, BLK, 0, stream>>>(uEmb, iEmb, cur, acc,
                                                         n4u, n4total);
        for (int l = 0; l < N_LAYERS; ++l) {
            hipMemsetAsync(nxt, 0, embBytes, stream);
            spmm_atomic_kernel<<<4096, BLK, 0, stream>>>(row, col, val, cur, nxt);
            acc_add_kernel<<<GRID_MEM, BLK, 0, stream>>>(acc, nxt, n4total);
            float* t = cur; cur = nxt; nxt = t;
        }
    }
}